// Round 2
// baseline (290.464 us; speedup 1.0000x reference)
//
#include <hip/hip_runtime.h>

#define N_NODES 50000
#define N_EDGES 800000
#define F 96
#define F4 24
#define NG 100
#define NC 8
#define LSTRIDE 200    // LDS A-tile row stride in ushorts (400B)
#define BK 64          // nodes per CSR bucket
#define NBUCK 782      // ceil(N_NODES/64)
#define NSUB 8         // sub-bins per bucket, key = blockIdx&7 (pseudo-XCD)
#define CAPS 256       // slots per sub-bin (mean 128, std ~11)
#define CAP 2048       // = NSUB*CAPS = 1<<11, slots per bucket
#define LBK 32         // nodes per layer block
#define NLB 1563       // ceil(N_NODES/32)
#define RPAD 128       // padded row length in ushorts (256B, 2 cache lines)

typedef __attribute__((ext_vector_type(8))) short bf16x8;
typedef __attribute__((ext_vector_type(4))) float f32x4;

__device__ inline unsigned short f2b(float f) {  // fp32 -> bf16 RNE
    unsigned int u = __float_as_uint(f);
    u += 0x7fffu + ((u >> 16) & 1u);
    return (unsigned short)(u >> 16);
}

__device__ inline void addu4(float* acc, uint4 u) {
    unsigned int uu[4] = {u.x, u.y, u.z, u.w};
#pragma unroll
    for (int q = 0; q < 4; q++) {
        acc[2 * q]     += __uint_as_float(uu[q] << 16);
        acc[2 * q + 1] += __uint_as_float(uu[q] & 0xffff0000u);
    }
}

// ---------- fused prep: x->bf16 padded rows + W pack + edge binfill ----------
__global__ __launch_bounds__(256) void k_prepfill(
    const float* __restrict__ x, const int* __restrict__ ei,
    const float* __restrict__ Wn1, const float* __restrict__ Ws1,
    const float* __restrict__ Wn2, const float* __restrict__ Ws2,
    const float* __restrict__ Wn3, const float* __restrict__ Ws3,
    unsigned short* __restrict__ xb_t, unsigned short* __restrict__ WbT,
    int* __restrict__ scur, unsigned int* __restrict__ binned) {
    int i = blockIdx.x * blockDim.x + threadIdx.x;
    if (i < N_NODES * 24) {  // node-major padded rows: xb_t[node][0..95], 128-ushort stride
        int node = i / 24;
        int c4 = i - node * 24;
        float4 v = *(const float4*)(x + (size_t)node * 96 + c4 * 4);
        ushort4 p;
        p.x = f2b(v.x); p.y = f2b(v.y); p.z = f2b(v.z); p.w = f2b(v.w);
        *(ushort4*)(xb_t + (size_t)node * RPAD + c4 * 4) = p;
    }
    if (i < N_EDGES) {
        int src = ei[i];
        int dst = ei[N_EDGES + i];
        int sub = (dst >> 6) * NSUB + (blockIdx.x & 7);
        int pos = atomicAdd(&scur[sub], 1);
        if (pos < CAPS)
            binned[((unsigned int)sub << 8) + pos] =
                ((unsigned int)(dst & 63) << 16) | (unsigned int)src;
    }
    if (i < 3 * 192 * 96) {
        int l = i / (192 * 96), r = i % (192 * 96);
        int n = r / 192, k = r % 192;
        const float* Wn = (l == 0) ? Wn1 : (l == 1) ? Wn2 : Wn3;
        const float* Ws = (l == 0) ? Ws1 : (l == 1) ? Ws2 : Ws3;
        float v = (k < 96) ? Wn[k * 96 + n] : Ws[(k - 96) * 96 + n];
        WbT[i] = f2b(v);
    }
}

// ---------- build per-bucket node-sorted CSR (once, reused by 3 layers) ----------
// csr_g[b*CAP + pos] = src (ushort); ndesc[node] = (localStart<<16) | deg
__global__ __launch_bounds__(256) void k_build(const unsigned int* __restrict__ binned,
                                               const int* __restrict__ scur,
                                               unsigned short* __restrict__ csr_g,
                                               int* __restrict__ ndesc) {
    __shared__ int hist[BK], sc[BK], loc[BK];
    __shared__ int spre[NSUB + 1];
    int t = threadIdx.x;
    int b = blockIdx.x;
    if (t < BK) hist[t] = 0;
    if (t == 0) {
        int s = 0;
#pragma unroll
        for (int k = 0; k < NSUB; k++) {
            spre[k] = s;
            int c = scur[b * NSUB + k];
            s += (c > CAPS) ? CAPS : c;
        }
        spre[NSUB] = s;
    }
    __syncthreads();
    int cnt = spre[NSUB];
    for (int i = t; i < cnt; i += 256) {
        int s = 0;
        while (spre[s + 1] <= i) s++;
        unsigned int v = binned[(((unsigned int)(b * NSUB + s)) << 8) + (i - spre[s])];
        atomicAdd(&hist[v >> 16], 1);
    }
    __syncthreads();
    if (t < BK) sc[t] = hist[t];
    __syncthreads();
    for (int off = 1; off < BK; off <<= 1) {
        int u = (t < BK && t >= off) ? sc[t - off] : 0;
        __syncthreads();
        if (t < BK) sc[t] += u;
        __syncthreads();
    }
    if (t < BK) {
        int excl = sc[t] - hist[t];
        loc[t] = excl;
        int node = (b << 6) + t;
        if (node < N_NODES) ndesc[node] = (excl << 16) | hist[t];
    }
    __syncthreads();
    for (int i = t; i < cnt; i += 256) {
        int s = 0;
        while (spre[s + 1] <= i) s++;
        unsigned int v = binned[(((unsigned int)(b * NSUB + s)) << 8) + (i - spre[s])];
        int pos = atomicAdd(&loc[v >> 16], 1);
        csr_g[(b << 11) + pos] = (unsigned short)(v & 0xFFFFu);
    }
}

// ---------- fused layer: barrier-free gather + MFMA (wave-independent) ----------
// hin: [N][RPAD] bf16 padded rows (features 0..95, pad 96..127 unused)
// One pass over edges per layer (all 96 features fused), 2-edge unroll = 6 dwordx4 in flight.
__global__ __launch_bounds__(128) void k_layer(
    const unsigned short* __restrict__ hin,
    const unsigned short* __restrict__ csr_g,
    const int* __restrict__ ndesc,
    const unsigned short* __restrict__ WbT,  // [96][192] bf16 (n-major)
    const float* __restrict__ bias,
    void* __restrict__ hout, int relu, int out_bf16) {
    __shared__ unsigned short A[LBK * LSTRIDE];  // 12.8 KB
    int t = threadIdx.x;
    int row0 = blockIdx.x * LBK;
    int nl = t >> 2;         // node-local 0..31 (wave w owns rows w*16..w*16+15)
    int q = t & 3;           // 16B chunk within each 64B third
    int node = row0 + nl;
    int meta = (node < N_NODES) ? ndesc[node] : 0;
    int deg = meta & 0xFFFF;
    int ebase = ((node >> 6) << 11) + (meta >> 16);

    int wave = t >> 6;
    int lane = t & 63;
    int m = lane & 15;
    int ko = (lane >> 4) * 8;

    // --- self row -> LDS immediately (frees regs, issues early) ---
    if (node < N_NODES) {
        const uint4* sp = (const uint4*)(hin + (size_t)node * RPAD + (q << 3));
        uint4 s0 = sp[0], s1 = sp[4], s2 = sp[8];  // bytes q*16 + {0,64,128}
        *(uint4*)&A[nl * LSTRIDE + 96 + 0 * 32 + q * 8] = s0;
        *(uint4*)&A[nl * LSTRIDE + 96 + 1 * 32 + q * 8] = s1;
        *(uint4*)&A[nl * LSTRIDE + 96 + 2 * 32 + q * 8] = s2;
    }

    // --- fused gather: all 96 features per edge in one pass ---
    float ac[24];
#pragma unroll
    for (int k = 0; k < 24; k++) ac[k] = 0.f;
    if (node < N_NODES) {
        int e = 0;
        for (; e + 2 <= deg; e += 2) {
            int s0 = csr_g[ebase + e];
            int s1 = csr_g[ebase + e + 1];
            const uint4* p0 = (const uint4*)(hin + ((size_t)s0 << 7) + (q << 3));
            const uint4* p1 = (const uint4*)(hin + ((size_t)s1 << 7) + (q << 3));
            uint4 a0 = p0[0], a1 = p0[4], a2 = p0[8];
            uint4 b0 = p1[0], b1 = p1[4], b2 = p1[8];
            addu4(ac + 0, a0); addu4(ac + 8, a1); addu4(ac + 16, a2);
            addu4(ac + 0, b0); addu4(ac + 8, b1); addu4(ac + 16, b2);
        }
        if (e < deg) {
            int s0 = csr_g[ebase + e];
            const uint4* p0 = (const uint4*)(hin + ((size_t)s0 << 7) + (q << 3));
            uint4 a0 = p0[0], a1 = p0[4], a2 = p0[8];
            addu4(ac + 0, a0); addu4(ac + 8, a1); addu4(ac + 16, a2);
        }
    }

    // --- pack aggregated features to LDS (same feature->slot map as before) ---
#pragma unroll
    for (int j = 0; j < 3; j++) {
        uint4 pk;
        pk.x = ((unsigned int)f2b(ac[j * 8 + 1]) << 16) | f2b(ac[j * 8 + 0]);
        pk.y = ((unsigned int)f2b(ac[j * 8 + 3]) << 16) | f2b(ac[j * 8 + 2]);
        pk.z = ((unsigned int)f2b(ac[j * 8 + 5]) << 16) | f2b(ac[j * 8 + 4]);
        pk.w = ((unsigned int)f2b(ac[j * 8 + 7]) << 16) | f2b(ac[j * 8 + 6]);
        *(uint4*)&A[nl * LSTRIDE + j * 32 + q * 8] = pk;
    }
    // no __syncthreads: rows w*16..w*16+15 are written and read by wave w only

    // --- MFMA: [agg | self] (K=192) x WbT ---
    f32x4 acc[6];
#pragma unroll
    for (int nt = 0; nt < 6; nt++) acc[nt] = (f32x4){0.f, 0.f, 0.f, 0.f};
#pragma unroll
    for (int j = 0; j < 3; j++) {
        bf16x8 a0 = *(bf16x8*)&A[(wave * 16 + m) * LSTRIDE + j * 32 + ko];
#pragma unroll
        for (int nt = 0; nt < 6; nt++) {
            bf16x8 bb = *(const bf16x8*)(WbT + (size_t)(nt * 16 + m) * 192 + j * 32 + ko);
            acc[nt] = __builtin_amdgcn_mfma_f32_16x16x32_bf16(a0, bb, acc[nt], 0, 0, 0);
        }
        bf16x8 a1 = *(bf16x8*)&A[(wave * 16 + m) * LSTRIDE + 96 + j * 32 + ko];
#pragma unroll
        for (int nt = 0; nt < 6; nt++) {
            bf16x8 bb = *(const bf16x8*)(WbT + (size_t)(nt * 16 + m) * 192 + 96 + j * 32 + ko);
            acc[nt] = __builtin_amdgcn_mfma_f32_16x16x32_bf16(a1, bb, acc[nt], 0, 0, 0);
        }
    }

#pragma unroll
    for (int nt = 0; nt < 6; nt++) {
        int col = nt * 16 + m;
        float bv = bias[col];
#pragma unroll
        for (int r = 0; r < 4; r++) {
            int rl = wave * 16 + ((lane >> 4) << 2) + r;
            int onode = row0 + rl;
            if (onode < N_NODES) {
                float v = acc[nt][r] + bv;
                if (relu) v = fmaxf(v, 0.f);
                if (out_bf16) {
                    ((unsigned short*)hout)[(size_t)onode * RPAD + col] = f2b(v);
                } else {
                    ((float*)hout)[(size_t)onode * F + col] = v;
                }
            }
        }
    }
}

// ---------- fused pool + head (graph bounds via binary search on sorted batch) ----------
#define NRG 20
__global__ __launch_bounds__(512) void k_pool(const float* __restrict__ h,
                                              const int* __restrict__ batch,
                                              const float* __restrict__ Wl,
                                              const float* __restrict__ bl,
                                              float* __restrict__ out) {
    __shared__ float4 red[NRG][F4 + 1];
    __shared__ float pool[F];
    __shared__ int bounds[2];
    int g = blockIdx.x;
    int t = threadIdx.x;
    if (t < 2) {
        int target = g + t;
        int lo = 0, hi = N_NODES;
        while (lo < hi) {
            int mid = (lo + hi) >> 1;
            if (batch[mid] < target) lo = mid + 1; else hi = mid;
        }
        bounds[t] = lo;
    }
    __syncthreads();
    int beg = bounds[0], end = bounds[1];
    int fc = t % F4;
    int rg = t / F4;
    const float4* h4 = (const float4*)h;
    if (rg < NRG) {
        float4 s = make_float4(0.f, 0.f, 0.f, 0.f);
        for (int r = beg + rg; r < end; r += NRG) {
            float4 v = h4[r * F4 + fc];
            s.x += v.x; s.y += v.y; s.z += v.z; s.w += v.w;
        }
        red[rg][fc] = s;
    }
    __syncthreads();
    if (t < F4) {
        float4 a = red[0][t];
#pragma unroll
        for (int i = 1; i < NRG; i++) {
            float4 v = red[i][t];
            a.x += v.x; a.y += v.y; a.z += v.z; a.w += v.w;
        }
        float inv = 1.f / fmaxf((float)(end - beg), 1.f);
        pool[t * 4 + 0] = a.x * inv;
        pool[t * 4 + 1] = a.y * inv;
        pool[t * 4 + 2] = a.z * inv;
        pool[t * 4 + 3] = a.w * inv;
    }
    __syncthreads();
    if (t < NC) {
        float s = bl[t];
#pragma unroll 8
        for (int k = 0; k < F; k++) s += pool[k] * Wl[k * NC + t];
        out[g * NC + t] = s;
    }
}

extern "C" void kernel_launch(void* const* d_in, const int* in_sizes, int n_in,
                              void* d_out, int out_size, void* d_ws, size_t ws_size,
                              hipStream_t stream) {
    const float* x   = (const float*)d_in[0];
    const int* ei    = (const int*)d_in[1];
    const int* batch = (const int*)d_in[3];
    const float* Wn1 = (const float*)d_in[4];
    const float* Ws1 = (const float*)d_in[5];
    const float* b1  = (const float*)d_in[6];
    const float* Wn2 = (const float*)d_in[7];
    const float* Ws2 = (const float*)d_in[8];
    const float* b2  = (const float*)d_in[9];
    const float* Wn3 = (const float*)d_in[10];
    const float* Ws3 = (const float*)d_in[11];
    const float* b3  = (const float*)d_in[12];
    const float* Wl  = (const float*)d_in[13];
    const float* bl  = (const float*)d_in[14];
    float* out = (float*)d_out;

    char* w = (char*)d_ws;
    float* h3f            = (float*)w;          w += (size_t)N_NODES * F * 4;
    unsigned short* xb_t  = (unsigned short*)w; w += (size_t)N_NODES * RPAD * 2;
    unsigned short* h1_t  = (unsigned short*)w; w += (size_t)N_NODES * RPAD * 2;
    unsigned short* h2_t  = (unsigned short*)w; w += (size_t)N_NODES * RPAD * 2;
    unsigned short* WbT   = (unsigned short*)w; w += (size_t)3 * 192 * 96 * 2;
    w = (char*)(((size_t)w + 255) & ~(size_t)255);
    int* scur            = (int*)w;            w += (size_t)NBUCK * NSUB * 4;
    unsigned int* binned = (unsigned int*)w;   w += (size_t)NBUCK * CAP * 4;
    unsigned short* csr_g = (unsigned short*)w; w += (size_t)NBUCK * CAP * 2;
    int* ndesc           = (int*)w;            w += (size_t)N_NODES * 4;

    hipMemsetAsync(scur, 0, (size_t)NBUCK * NSUB * 4, stream);
    k_prepfill<<<(N_NODES * 24 + 255) / 256, 256, 0, stream>>>(
        x, ei, Wn1, Ws1, Wn2, Ws2, Wn3, Ws3, xb_t, WbT, scur, binned);
    k_build<<<NBUCK, 256, 0, stream>>>(binned, scur, csr_g, ndesc);

    k_layer<<<NLB, 128, 0, stream>>>(xb_t, csr_g, ndesc, WbT,                b1, h1_t, 1, 1);
    k_layer<<<NLB, 128, 0, stream>>>(h1_t, csr_g, ndesc, WbT + 192 * 96,     b2, h2_t, 1, 1);
    k_layer<<<NLB, 128, 0, stream>>>(h2_t, csr_g, ndesc, WbT + 2 * 192 * 96, b3, h3f, 0, 0);

    k_pool<<<NG, 512, 0, stream>>>(h3f, batch, Wl, bl, out);
}

// Round 3
// 279.070 us; speedup vs baseline: 1.0408x; 1.0408x over previous
//
#include <hip/hip_runtime.h>

#define N_NODES 50000
#define N_EDGES 800000
#define F 96
#define F4 24
#define NG 100
#define NC 8
#define LSTRIDE 200    // LDS A-tile row stride in ushorts (400B)
#define PSTR 100       // LDS partial-sum row stride in floats (400B)
#define DMAX 64        // CSR row capacity per node (Poisson(16): P(deg>64) ~ 1e-20)
#define LBK 16         // nodes per layer block
#define NLB 3125       // 50000/16 exactly -> no tail block
#define RPAD 128       // padded feature row length in ushorts (256B, 2 cache lines)
#define NSLC 8         // pool row-slices

typedef __attribute__((ext_vector_type(8))) short bf16x8;
typedef __attribute__((ext_vector_type(4))) float f32x4;

__device__ inline unsigned short f2b(float f) {  // fp32 -> bf16 RNE
    unsigned int u = __float_as_uint(f);
    u += 0x7fffu + ((u >> 16) & 1u);
    return (unsigned short)(u >> 16);
}

__device__ inline void addu4(float* acc, uint4 u) {
    unsigned int uu[4] = {u.x, u.y, u.z, u.w};
#pragma unroll
    for (int q = 0; q < 4; q++) {
        acc[2 * q]     += __uint_as_float(uu[q] << 16);
        acc[2 * q + 1] += __uint_as_float(uu[q] & 0xffff0000u);
    }
}

// ---------- fused prep: x->bf16 padded rows + W pack + DIRECT per-node CSR ----------
// ndesc[node] = in-degree (atomic counter); csr_g[node*64 + pos] = src.
// No k_build pass needed: k_layer uses deg=ndesc[n], ebase=n*64.
__global__ __launch_bounds__(256) void k_prepfill(
    const float* __restrict__ x, const int* __restrict__ ei,
    const float* __restrict__ Wn1, const float* __restrict__ Ws1,
    const float* __restrict__ Wn2, const float* __restrict__ Ws2,
    const float* __restrict__ Wn3, const float* __restrict__ Ws3,
    unsigned short* __restrict__ xb_t, unsigned short* __restrict__ WbT,
    int* __restrict__ ndesc, unsigned short* __restrict__ csr_g) {
    int i = blockIdx.x * blockDim.x + threadIdx.x;
    if (i < N_NODES * 24) {  // node-major padded rows: xb_t[node][0..95], 128-ushort stride
        int node = i / 24;
        int c4 = i - node * 24;
        float4 v = *(const float4*)(x + (size_t)node * 96 + c4 * 4);
        ushort4 p;
        p.x = f2b(v.x); p.y = f2b(v.y); p.z = f2b(v.z); p.w = f2b(v.w);
        *(ushort4*)(xb_t + (size_t)node * RPAD + c4 * 4) = p;
    }
    if (i < N_EDGES) {
        int src = ei[i];
        int dst = ei[N_EDGES + i];
        int pos = atomicAdd(&ndesc[dst], 1);
        if (pos < DMAX)
            csr_g[((size_t)dst << 6) + pos] = (unsigned short)src;
    }
    if (i < 3 * 192 * 96) {
        int l = i / (192 * 96), r = i % (192 * 96);
        int n = r / 192, k = r % 192;
        const float* Wn = (l == 0) ? Wn1 : (l == 1) ? Wn2 : Wn3;
        const float* Ws = (l == 0) ? Ws1 : (l == 1) ? Ws2 : Ws3;
        float v = (k < 96) ? Wn[k * 96 + n] : Ws[(k - 96) * 96 + n];
        WbT[i] = f2b(v);
    }
}

// ---------- fused layer: split-gather (8 threads/node) + MFMA ----------
// hin: [N][RPAD] bf16 padded rows. 16 nodes/block, 128 threads:
//   nl = t>>3 (node), h = (t>>2)&1 (edge parity half), q = t&3 (16B feature chunk).
// Each half accumulates its parity's edges in f32; halves combine via LDS P;
// then 2 waves split the 6 nt output tiles (3 each) over the shared 16-row A tile.
__global__ __launch_bounds__(128) void k_layer(
    const unsigned short* __restrict__ hin,
    const unsigned short* __restrict__ csr_g,
    const int* __restrict__ ndesc,
    const unsigned short* __restrict__ WbT,  // [96][192] bf16 (n-major)
    const float* __restrict__ bias,
    void* __restrict__ hout, int relu, int out_bf16) {
    __shared__ unsigned short A[LBK * LSTRIDE];  // 6.4 KB
    __shared__ float P[LBK * PSTR];              // 6.4 KB
    int t = threadIdx.x;
    int row0 = blockIdx.x * LBK;
    int nl = t >> 3;
    int h = (t >> 2) & 1;
    int q = t & 3;
    int node = row0 + nl;                 // always < N_NODES (50000 = 3125*16)
    int deg = ndesc[node];
    if (deg > DMAX) deg = DMAX;
    size_t ebase = (size_t)node << 6;

    // --- self row -> LDS (h==0 lanes cover all 192B) ---
    if (h == 0) {
        const uint4* sp = (const uint4*)(hin + (size_t)node * RPAD + (q << 3));
        uint4 s0 = sp[0], s1 = sp[4], s2 = sp[8];
        *(uint4*)&A[nl * LSTRIDE + 96 + 0 * 32 + q * 8] = s0;
        *(uint4*)&A[nl * LSTRIDE + 96 + 1 * 32 + q * 8] = s1;
        *(uint4*)&A[nl * LSTRIDE + 96 + 2 * 32 + q * 8] = s2;
    }

    // --- gather: half h handles edges e ≡ h (mod 2), 2-edge unroll ---
    float ac[24];
#pragma unroll
    for (int k = 0; k < 24; k++) ac[k] = 0.f;
    {
        int e = h;
        for (; e + 3 <= deg; e += 4) {
            int s0 = csr_g[ebase + e];
            int s1 = csr_g[ebase + e + 2];
            const uint4* p0 = (const uint4*)(hin + ((size_t)s0 << 7) + (q << 3));
            const uint4* p1 = (const uint4*)(hin + ((size_t)s1 << 7) + (q << 3));
            uint4 a0 = p0[0], a1 = p0[4], a2 = p0[8];
            uint4 b0 = p1[0], b1 = p1[4], b2 = p1[8];
            addu4(ac + 0, a0); addu4(ac + 8, a1); addu4(ac + 16, a2);
            addu4(ac + 0, b0); addu4(ac + 8, b1); addu4(ac + 16, b2);
        }
        if (e < deg) {
            int s0 = csr_g[ebase + e];
            const uint4* p0 = (const uint4*)(hin + ((size_t)s0 << 7) + (q << 3));
            uint4 a0 = p0[0], a1 = p0[4], a2 = p0[8];
            addu4(ac + 0, a0); addu4(ac + 8, a1); addu4(ac + 16, a2);
        }
    }

    // --- combine halves: h=1 writes partials, h=0 adds + packs bf16 into A ---
    if (h == 1) {
#pragma unroll
        for (int j = 0; j < 3; j++) {
            *(float4*)&P[nl * PSTR + j * 32 + q * 8] =
                make_float4(ac[j * 8 + 0], ac[j * 8 + 1], ac[j * 8 + 2], ac[j * 8 + 3]);
            *(float4*)&P[nl * PSTR + j * 32 + q * 8 + 4] =
                make_float4(ac[j * 8 + 4], ac[j * 8 + 5], ac[j * 8 + 6], ac[j * 8 + 7]);
        }
    }
    __syncthreads();
    if (h == 0) {
#pragma unroll
        for (int j = 0; j < 3; j++) {
            float4 u = *(float4*)&P[nl * PSTR + j * 32 + q * 8];
            float4 v = *(float4*)&P[nl * PSTR + j * 32 + q * 8 + 4];
            uint4 pk;
            pk.x = ((unsigned int)f2b(ac[j * 8 + 1] + u.y) << 16) | f2b(ac[j * 8 + 0] + u.x);
            pk.y = ((unsigned int)f2b(ac[j * 8 + 3] + u.w) << 16) | f2b(ac[j * 8 + 2] + u.z);
            pk.z = ((unsigned int)f2b(ac[j * 8 + 5] + v.y) << 16) | f2b(ac[j * 8 + 4] + v.x);
            pk.w = ((unsigned int)f2b(ac[j * 8 + 7] + v.w) << 16) | f2b(ac[j * 8 + 6] + v.z);
            *(uint4*)&A[nl * LSTRIDE + j * 32 + q * 8] = pk;
        }
    }
    __syncthreads();

    // --- MFMA: wave w computes nt = 3w..3w+2 over the 16-row A tile (K=192) ---
    int wave = t >> 6;
    int lane = t & 63;
    int m = lane & 15;
    int ko = (lane >> 4) * 8;
    f32x4 acc[3];
#pragma unroll
    for (int i = 0; i < 3; i++) acc[i] = (f32x4){0.f, 0.f, 0.f, 0.f};
#pragma unroll
    for (int j = 0; j < 3; j++) {
        bf16x8 a0 = *(bf16x8*)&A[m * LSTRIDE + j * 32 + ko];
#pragma unroll
        for (int i = 0; i < 3; i++) {
            int nt = wave * 3 + i;
            bf16x8 bb = *(const bf16x8*)(WbT + (size_t)(nt * 16 + m) * 192 + j * 32 + ko);
            acc[i] = __builtin_amdgcn_mfma_f32_16x16x32_bf16(a0, bb, acc[i], 0, 0, 0);
        }
        bf16x8 a1 = *(bf16x8*)&A[m * LSTRIDE + 96 + j * 32 + ko];
#pragma unroll
        for (int i = 0; i < 3; i++) {
            int nt = wave * 3 + i;
            bf16x8 bb = *(const bf16x8*)(WbT + (size_t)(nt * 16 + m) * 192 + 96 + j * 32 + ko);
            acc[i] = __builtin_amdgcn_mfma_f32_16x16x32_bf16(a1, bb, acc[i], 0, 0, 0);
        }
    }

#pragma unroll
    for (int i = 0; i < 3; i++) {
        int col = (wave * 3 + i) * 16 + m;
        float bv = bias[col];
#pragma unroll
        for (int r = 0; r < 4; r++) {
            int rl = ((lane >> 4) << 2) + r;
            int onode = row0 + rl;
            float v = acc[i][r] + bv;
            if (relu) v = fmaxf(v, 0.f);
            if (out_bf16) {
                ((unsigned short*)hout)[(size_t)onode * RPAD + col] = f2b(v);
            } else {
                ((float*)hout)[(size_t)onode * F + col] = v;
            }
        }
    }
}

// ---------- pool stage 1: 8 row-slices per graph -> partial sums ----------
__global__ __launch_bounds__(256) void k_poolp(const float* __restrict__ h,
                                               const int* __restrict__ batch,
                                               float* __restrict__ pools) {
    __shared__ float4 red[10][F4 + 1];
    __shared__ int bounds[2];
    int g = blockIdx.x >> 3;
    int s = blockIdx.x & 7;
    int t = threadIdx.x;
    if (t < 2) {
        int target = g + t;
        int lo = 0, hi = N_NODES;
        while (lo < hi) {
            int mid = (lo + hi) >> 1;
            if (batch[mid] < target) lo = mid + 1; else hi = mid;
        }
        bounds[t] = lo;
    }
    __syncthreads();
    int beg = bounds[0], end = bounds[1];
    int fc = t % F4;
    int rg = t / F4;  // 0..9 active (t<240)
    const float4* h4 = (const float4*)h;
    if (rg < 10) {
        float4 ss = make_float4(0.f, 0.f, 0.f, 0.f);
        for (int r = beg + s + 8 * rg; r < end; r += 8 * 10) {
            float4 v = h4[r * F4 + fc];
            ss.x += v.x; ss.y += v.y; ss.z += v.z; ss.w += v.w;
        }
        red[rg][fc] = ss;
    }
    __syncthreads();
    if (t < F4) {
        float4 a = red[0][t];
#pragma unroll
        for (int i = 1; i < 10; i++) {
            float4 v = red[i][t];
            a.x += v.x; a.y += v.y; a.z += v.z; a.w += v.w;
        }
        ((float4*)pools)[(s * NG + g) * F4 + t] = a;
    }
}

// ---------- pool stage 2 + head ----------
__global__ __launch_bounds__(64) void k_head(const float* __restrict__ pools,
                                             const int* __restrict__ batch,
                                             const float* __restrict__ Wl,
                                             const float* __restrict__ bl,
                                             float* __restrict__ out) {
    __shared__ float pool[F];
    __shared__ int bounds[2];
    int g = blockIdx.x;
    int t = threadIdx.x;
    if (t < 2) {
        int target = g + t;
        int lo = 0, hi = N_NODES;
        while (lo < hi) {
            int mid = (lo + hi) >> 1;
            if (batch[mid] < target) lo = mid + 1; else hi = mid;
        }
        bounds[t] = lo;
    }
    __syncthreads();
    float inv = 1.f / fmaxf((float)(bounds[1] - bounds[0]), 1.f);
    if (t < F4) {
        float4 a = make_float4(0.f, 0.f, 0.f, 0.f);
#pragma unroll
        for (int s = 0; s < NSLC; s++) {
            float4 v = ((const float4*)pools)[(s * NG + g) * F4 + t];
            a.x += v.x; a.y += v.y; a.z += v.z; a.w += v.w;
        }
        pool[t * 4 + 0] = a.x * inv;
        pool[t * 4 + 1] = a.y * inv;
        pool[t * 4 + 2] = a.z * inv;
        pool[t * 4 + 3] = a.w * inv;
    }
    __syncthreads();
    if (t < NC) {
        float s = bl[t];
#pragma unroll 8
        for (int k = 0; k < F; k++) s += pool[k] * Wl[k * NC + t];
        out[g * NC + t] = s;
    }
}

extern "C" void kernel_launch(void* const* d_in, const int* in_sizes, int n_in,
                              void* d_out, int out_size, void* d_ws, size_t ws_size,
                              hipStream_t stream) {
    const float* x   = (const float*)d_in[0];
    const int* ei    = (const int*)d_in[1];
    const int* batch = (const int*)d_in[3];
    const float* Wn1 = (const float*)d_in[4];
    const float* Ws1 = (const float*)d_in[5];
    const float* b1  = (const float*)d_in[6];
    const float* Wn2 = (const float*)d_in[7];
    const float* Ws2 = (const float*)d_in[8];
    const float* b2  = (const float*)d_in[9];
    const float* Wn3 = (const float*)d_in[10];
    const float* Ws3 = (const float*)d_in[11];
    const float* b3  = (const float*)d_in[12];
    const float* Wl  = (const float*)d_in[13];
    const float* bl  = (const float*)d_in[14];
    float* out = (float*)d_out;

    char* w = (char*)d_ws;
    float* h3f            = (float*)w;          w += (size_t)N_NODES * F * 4;
    unsigned short* xb_t  = (unsigned short*)w; w += (size_t)N_NODES * RPAD * 2;
    unsigned short* h1_t  = (unsigned short*)w; w += (size_t)N_NODES * RPAD * 2;
    unsigned short* h2_t  = (unsigned short*)w; w += (size_t)N_NODES * RPAD * 2;
    unsigned short* WbT   = (unsigned short*)w; w += (size_t)3 * 192 * 96 * 2;
    w = (char*)(((size_t)w + 255) & ~(size_t)255);
    unsigned short* csr_g = (unsigned short*)w; w += (size_t)N_NODES * DMAX * 2;
    int* ndesc           = (int*)w;             w += (size_t)N_NODES * 4;
    w = (char*)(((size_t)w + 255) & ~(size_t)255);
    float* pools         = (float*)w;           w += (size_t)NSLC * NG * F * 4;

    hipMemsetAsync(ndesc, 0, (size_t)N_NODES * 4, stream);
    k_prepfill<<<(N_NODES * 24 + 255) / 256, 256, 0, stream>>>(
        x, ei, Wn1, Ws1, Wn2, Ws2, Wn3, Ws3, xb_t, WbT, ndesc, csr_g);

    k_layer<<<NLB, 128, 0, stream>>>(xb_t, csr_g, ndesc, WbT,                b1, h1_t, 1, 1);
    k_layer<<<NLB, 128, 0, stream>>>(h1_t, csr_g, ndesc, WbT + 192 * 96,     b2, h2_t, 1, 1);
    k_layer<<<NLB, 128, 0, stream>>>(h2_t, csr_g, ndesc, WbT + 2 * 192 * 96, b3, h3f, 0, 0);

    k_poolp<<<NG * NSLC, 256, 0, stream>>>(h3f, batch, pools);
    k_head<<<NG, 64, 0, stream>>>(pools, batch, Wl, bl, out);
}

// Round 4
// 274.850 us; speedup vs baseline: 1.0568x; 1.0154x over previous
//
#include <hip/hip_runtime.h>

#define N_NODES 50000
#define N_EDGES 800000
#define F 96
#define F4 24
#define NG 100
#define NC 8
#define LSTRIDE 200    // LDS A-tile row stride in ushorts (400B)
#define DMAX 64        // CSR row capacity per node (Poisson(16): P(deg>64) ~ 1e-20)
#define LBK 16         // nodes per layer block
#define NLB 3125       // 50000/16 exactly -> no tail block
#define RPAD 128       // padded feature row length in ushorts (256B, 2 cache lines)

typedef __attribute__((ext_vector_type(8))) short bf16x8;
typedef __attribute__((ext_vector_type(4))) float f32x4;

__device__ inline unsigned short f2b(float f) {  // fp32 -> bf16 RNE
    unsigned int u = __float_as_uint(f);
    u += 0x7fffu + ((u >> 16) & 1u);
    return (unsigned short)(u >> 16);
}

__device__ inline void addu4(float* acc, uint4 u) {
    unsigned int uu[4] = {u.x, u.y, u.z, u.w};
#pragma unroll
    for (int q = 0; q < 4; q++) {
        acc[2 * q]     += __uint_as_float(uu[q] << 16);
        acc[2 * q + 1] += __uint_as_float(uu[q] & 0xffff0000u);
    }
}

// ---------- conv: x->bf16 padded rows + W pack ----------
__global__ __launch_bounds__(256) void k_conv(
    const float* __restrict__ x,
    const float* __restrict__ Wn1, const float* __restrict__ Ws1,
    const float* __restrict__ Wn2, const float* __restrict__ Ws2,
    const float* __restrict__ Wn3, const float* __restrict__ Ws3,
    unsigned short* __restrict__ xb_t, unsigned short* __restrict__ WbT) {
    int i = blockIdx.x * blockDim.x + threadIdx.x;
    if (i < N_NODES * 24) {  // node-major padded rows: xb_t[node][0..95], 128-ushort stride
        int node = i / 24;
        int c4 = i - node * 24;
        float4 v = *(const float4*)(x + (size_t)node * 96 + c4 * 4);
        ushort4 p;
        p.x = f2b(v.x); p.y = f2b(v.y); p.z = f2b(v.z); p.w = f2b(v.w);
        *(ushort4*)(xb_t + (size_t)node * RPAD + c4 * 4) = p;
    }
    if (i < 3 * 192 * 96) {
        int l = i / (192 * 96), r = i % (192 * 96);
        int n = r / 192, k = r % 192;
        const float* Wn = (l == 0) ? Wn1 : (l == 1) ? Wn2 : Wn3;
        const float* Ws = (l == 0) ? Ws1 : (l == 1) ? Ws2 : Ws3;
        float v = (k < 96) ? Wn[k * 96 + n] : Ws[(k - 96) * 96 + n];
        WbT[i] = f2b(v);
    }
}

// ---------- edges: direct per-node CSR via atomic counters ----------
__global__ __launch_bounds__(256) void k_edges(
    const int* __restrict__ ei,
    int* __restrict__ ndesc, unsigned short* __restrict__ csr_g) {
    int i = blockIdx.x * blockDim.x + threadIdx.x;
    if (i < N_EDGES) {
        int src = ei[i];
        int dst = ei[N_EDGES + i];
        int pos = atomicAdd(&ndesc[dst], 1);
        if (pos < DMAX)
            csr_g[((size_t)dst << 6) + pos] = (unsigned short)src;
    }
}

// ---------- fused layer: 16 threads/node (4-way edge split, shfl combine) + MFMA ----------
// hin: [N][RPAD] bf16 padded rows. 16 nodes/block, 256 threads (4 waves):
//   nl = t>>4 (node 0..15), h = (t>>2)&3 (edge quarter, stride 4), q = t&3 (16B chunk).
// Quarters combine via shfl_xor(4/8) in-wave (lane bits [3:2] = h). One barrier.
// out_bf16==0 (layer 3): pooling fused — per-block LDS f32 accum over the <=2
// graphs the block spans, then ~192 global atomicAdds into pools[g][96].
__global__ __launch_bounds__(256, 5) void k_layer(
    const unsigned short* __restrict__ hin,
    const unsigned short* __restrict__ csr_g,
    const int* __restrict__ ndesc,
    const unsigned short* __restrict__ WbT,  // [96][192] bf16 (n-major)
    const float* __restrict__ bias,
    unsigned short* __restrict__ hout, int relu, int out_bf16,
    const int* __restrict__ batch, float* __restrict__ pools) {
    __shared__ unsigned short A[LBK * LSTRIDE];  // 6.4 KB
    __shared__ float pl[2 * F];                  // layer-3 pooling accum
    int t = threadIdx.x;
    int row0 = blockIdx.x * LBK;
    int nl = t >> 4;
    int h = (t >> 2) & 3;
    int q = t & 3;
    int node = row0 + nl;                 // always < N_NODES (50000 = 3125*16)
    int deg = ndesc[node];
    if (deg > DMAX) deg = DMAX;
    size_t ebase = (size_t)node << 6;

    if (!out_bf16 && t < 2 * F) pl[t] = 0.f;

    // --- self row -> LDS (h==0 lanes cover all 192B) ---
    if (h == 0) {
        const uint4* sp = (const uint4*)(hin + (size_t)node * RPAD + (q << 3));
        uint4 s0 = sp[0], s1 = sp[4], s2 = sp[8];
        *(uint4*)&A[nl * LSTRIDE + 96 + 0 * 32 + q * 8] = s0;
        *(uint4*)&A[nl * LSTRIDE + 96 + 1 * 32 + q * 8] = s1;
        *(uint4*)&A[nl * LSTRIDE + 96 + 2 * 32 + q * 8] = s2;
    }

    // --- gather: quarter h handles edges e = h, h+4, h+8, ... (2-edge unroll) ---
    float ac[24];
#pragma unroll
    for (int k = 0; k < 24; k++) ac[k] = 0.f;
    {
        int e = h;
        for (; e + 4 < deg; e += 8) {
            int s0 = csr_g[ebase + e];
            int s1 = csr_g[ebase + e + 4];
            const uint4* p0 = (const uint4*)(hin + ((size_t)s0 << 7) + (q << 3));
            const uint4* p1 = (const uint4*)(hin + ((size_t)s1 << 7) + (q << 3));
            uint4 a0 = p0[0], a1 = p0[4], a2 = p0[8];
            uint4 b0 = p1[0], b1 = p1[4], b2 = p1[8];
            addu4(ac + 0, a0); addu4(ac + 8, a1); addu4(ac + 16, a2);
            addu4(ac + 0, b0); addu4(ac + 8, b1); addu4(ac + 16, b2);
        }
        if (e < deg) {
            int s0 = csr_g[ebase + e];
            const uint4* p0 = (const uint4*)(hin + ((size_t)s0 << 7) + (q << 3));
            uint4 a0 = p0[0], a1 = p0[4], a2 = p0[8];
            addu4(ac + 0, a0); addu4(ac + 8, a1); addu4(ac + 16, a2);
        }
    }

    // --- combine quarters in-wave: lane bits [3:2] = h ---
#pragma unroll
    for (int k = 0; k < 24; k++) {
        ac[k] += __shfl_xor(ac[k], 4, 64);
        ac[k] += __shfl_xor(ac[k], 8, 64);
    }

    // --- pack aggregated features to LDS (h==0 lanes) ---
    if (h == 0) {
#pragma unroll
        for (int j = 0; j < 3; j++) {
            uint4 pk;
            pk.x = ((unsigned int)f2b(ac[j * 8 + 1]) << 16) | f2b(ac[j * 8 + 0]);
            pk.y = ((unsigned int)f2b(ac[j * 8 + 3]) << 16) | f2b(ac[j * 8 + 2]);
            pk.z = ((unsigned int)f2b(ac[j * 8 + 5]) << 16) | f2b(ac[j * 8 + 4]);
            pk.w = ((unsigned int)f2b(ac[j * 8 + 7]) << 16) | f2b(ac[j * 8 + 6]);
            *(uint4*)&A[nl * LSTRIDE + j * 32 + q * 8] = pk;
        }
    }
    __syncthreads();

    // --- MFMA: wave w computes nt in {w, w+4} (waves 0,1: 2 tiles; 2,3: 1) ---
    int wave = t >> 6;
    int lane = t & 63;
    int m = lane & 15;
    int ko = (lane >> 4) * 8;
    f32x4 acc[2];
    acc[0] = (f32x4){0.f, 0.f, 0.f, 0.f};
    acc[1] = (f32x4){0.f, 0.f, 0.f, 0.f};
    int ntc = (wave < 2) ? 2 : 1;
#pragma unroll
    for (int j = 0; j < 3; j++) {
        bf16x8 a0 = *(bf16x8*)&A[m * LSTRIDE + j * 32 + ko];
        bf16x8 a1 = *(bf16x8*)&A[m * LSTRIDE + 96 + j * 32 + ko];
        for (int ii = 0; ii < ntc; ii++) {
            int nt = wave + ii * 4;
            bf16x8 b0 = *(const bf16x8*)(WbT + (size_t)(nt * 16 + m) * 192 + j * 32 + ko);
            acc[ii] = __builtin_amdgcn_mfma_f32_16x16x32_bf16(a0, b0, acc[ii], 0, 0, 0);
            bf16x8 b1 = *(const bf16x8*)(WbT + (size_t)(nt * 16 + m) * 192 + 96 + j * 32 + ko);
            acc[ii] = __builtin_amdgcn_mfma_f32_16x16x32_bf16(a1, b1, acc[ii], 0, 0, 0);
        }
    }

    if (out_bf16) {
        for (int ii = 0; ii < ntc; ii++) {
            int col = (wave + ii * 4) * 16 + m;
            float bv = bias[col];
#pragma unroll
            for (int r = 0; r < 4; r++) {
                int rl = ((lane >> 4) << 2) + r;
                int onode = row0 + rl;
                float v = acc[ii][r] + bv;
                if (relu) v = fmaxf(v, 0.f);
                hout[(size_t)onode * RPAD + col] = f2b(v);
            }
        }
    } else {
        // layer 3: fused mean-pool accumulation (block spans <=2 graphs normally)
        int gA = batch[row0];
        for (int ii = 0; ii < ntc; ii++) {
            int col = (wave + ii * 4) * 16 + m;
            float bv = bias[col];
            float s0 = 0.f, s1 = 0.f;
#pragma unroll
            for (int r = 0; r < 4; r++) {
                int rl = ((lane >> 4) << 2) + r;
                int onode = row0 + rl;
                float v = acc[ii][r] + bv;
                int slot = batch[onode] - gA;
                if (slot == 0) s0 += v;
                else if (slot == 1) s1 += v;
                else atomicAdd(&pools[(size_t)(gA + slot) * F + col], v);  // freak case
            }
            if (s0 != 0.f) atomicAdd(&pl[col], s0);
            if (s1 != 0.f) atomicAdd(&pl[F + col], s1);
        }
        __syncthreads();
        if (t < 2 * F) {
            int gl = t / F;
            float v = pl[t];
            if (v != 0.f && gA + gl < NG)
                atomicAdd(&pools[(size_t)(gA + gl) * F + (t % F)], v);
        }
    }
}

// ---------- head: divide pooled sums by counts, apply classifier ----------
__global__ __launch_bounds__(128) void k_head(const float* __restrict__ pools,
                                              const int* __restrict__ batch,
                                              const float* __restrict__ Wl,
                                              const float* __restrict__ bl,
                                              float* __restrict__ out) {
    __shared__ float pool[F];
    __shared__ int bounds[2];
    int g = blockIdx.x;
    int t = threadIdx.x;
    if (t < 2) {
        int target = g + t;
        int lo = 0, hi = N_NODES;
        while (lo < hi) {
            int mid = (lo + hi) >> 1;
            if (batch[mid] < target) lo = mid + 1; else hi = mid;
        }
        bounds[t] = lo;
    }
    __syncthreads();
    float inv = 1.f / fmaxf((float)(bounds[1] - bounds[0]), 1.f);
    if (t < F) pool[t] = pools[(size_t)g * F + t] * inv;
    __syncthreads();
    if (t < NC) {
        float s = bl[t];
#pragma unroll 8
        for (int k = 0; k < F; k++) s += pool[k] * Wl[k * NC + t];
        out[g * NC + t] = s;
    }
}

extern "C" void kernel_launch(void* const* d_in, const int* in_sizes, int n_in,
                              void* d_out, int out_size, void* d_ws, size_t ws_size,
                              hipStream_t stream) {
    const float* x   = (const float*)d_in[0];
    const int* ei    = (const int*)d_in[1];
    const int* batch = (const int*)d_in[3];
    const float* Wn1 = (const float*)d_in[4];
    const float* Ws1 = (const float*)d_in[5];
    const float* b1  = (const float*)d_in[6];
    const float* Wn2 = (const float*)d_in[7];
    const float* Ws2 = (const float*)d_in[8];
    const float* b2  = (const float*)d_in[9];
    const float* Wn3 = (const float*)d_in[10];
    const float* Ws3 = (const float*)d_in[11];
    const float* b3  = (const float*)d_in[12];
    const float* Wl  = (const float*)d_in[13];
    const float* bl  = (const float*)d_in[14];
    float* out = (float*)d_out;

    char* w = (char*)d_ws;
    unsigned short* xb_t  = (unsigned short*)w; w += (size_t)N_NODES * RPAD * 2;
    unsigned short* h1_t  = (unsigned short*)w; w += (size_t)N_NODES * RPAD * 2;
    unsigned short* h2_t  = (unsigned short*)w; w += (size_t)N_NODES * RPAD * 2;
    unsigned short* WbT   = (unsigned short*)w; w += (size_t)3 * 192 * 96 * 2;
    w = (char*)(((size_t)w + 255) & ~(size_t)255);
    unsigned short* csr_g = (unsigned short*)w; w += (size_t)N_NODES * DMAX * 2;
    int* ndesc           = (int*)w;             w += (size_t)N_NODES * 4;
    float* pools         = (float*)w;           w += (size_t)NG * F * 4;  // adjacent to ndesc: one memset

    hipMemsetAsync(ndesc, 0, (size_t)N_NODES * 4 + (size_t)NG * F * 4, stream);
    k_edges<<<(N_EDGES + 255) / 256, 256, 0, stream>>>(ei, ndesc, csr_g);
    k_conv<<<(N_NODES * 24 + 255) / 256, 256, 0, stream>>>(
        x, Wn1, Ws1, Wn2, Ws2, Wn3, Ws3, xb_t, WbT);

    k_layer<<<NLB, 256, 0, stream>>>(xb_t, csr_g, ndesc, WbT,                b1, h1_t, 1, 1, batch, pools);
    k_layer<<<NLB, 256, 0, stream>>>(h1_t, csr_g, ndesc, WbT + 192 * 96,     b2, h2_t, 1, 1, batch, pools);
    k_layer<<<NLB, 256, 0, stream>>>(h2_t, csr_g, ndesc, WbT + 2 * 192 * 96, b3, h2_t, 0, 0, batch, pools);

    k_head<<<NG, 128, 0, stream>>>(pools, batch, Wl, bl, out);
}

// Round 5
// 271.809 us; speedup vs baseline: 1.0686x; 1.0112x over previous
//
#include <hip/hip_runtime.h>

#define N_NODES 50000
#define N_EDGES 800000
#define F 96
#define F4 24
#define NG 100
#define NC 8
#define LSTRIDE 200    // LDS A-tile row stride in ushorts (400B)
#define DMAX 64        // CSR row capacity per node (Poisson(16): P(deg>64) ~ 1e-20)
#define LBK 16         // nodes per layer block
#define NLB 3125       // 50000/16 exactly -> no tail block
#define RPAD 128       // padded feature row length in ushorts (256B, 2 cache lines)

typedef __attribute__((ext_vector_type(8))) short bf16x8;
typedef __attribute__((ext_vector_type(4))) float f32x4;

__device__ inline unsigned short f2b(float f) {  // fp32 -> bf16 RNE
    unsigned int u = __float_as_uint(f);
    u += 0x7fffu + ((u >> 16) & 1u);
    return (unsigned short)(u >> 16);
}

__device__ inline void addu4(float* acc, uint4 u) {
    unsigned int uu[4] = {u.x, u.y, u.z, u.w};
#pragma unroll
    for (int q = 0; q < 4; q++) {
        acc[2 * q]     += __uint_as_float(uu[q] << 16);
        acc[2 * q + 1] += __uint_as_float(uu[q] & 0xffff0000u);
    }
}

// ---------- fused prep: x->bf16 rows + W pack + direct per-node CSR ----------
// Fused on purpose: the conv/W work of co-resident threads hides the edge
// atomic+scatter latency (split version measured +20us slower, r4).
__global__ __launch_bounds__(256) void k_prepfill(
    const float* __restrict__ x, const int* __restrict__ ei,
    const float* __restrict__ Wn1, const float* __restrict__ Ws1,
    const float* __restrict__ Wn2, const float* __restrict__ Ws2,
    const float* __restrict__ Wn3, const float* __restrict__ Ws3,
    unsigned short* __restrict__ xb_t, unsigned short* __restrict__ WbT,
    int* __restrict__ ndesc, unsigned short* __restrict__ csr_g) {
    int i = blockIdx.x * blockDim.x + threadIdx.x;
    if (i < N_NODES * 24) {  // node-major padded rows: xb_t[node][0..95], 128-ushort stride
        int node = i / 24;
        int c4 = i - node * 24;
        float4 v = *(const float4*)(x + (size_t)node * 96 + c4 * 4);
        ushort4 p;
        p.x = f2b(v.x); p.y = f2b(v.y); p.z = f2b(v.z); p.w = f2b(v.w);
        *(ushort4*)(xb_t + (size_t)node * RPAD + c4 * 4) = p;
    }
    if (i < N_EDGES) {
        int src = ei[i];
        int dst = ei[N_EDGES + i];
        int pos = atomicAdd(&ndesc[dst], 1);
        if (pos < DMAX)
            csr_g[((size_t)dst << 6) + pos] = (unsigned short)src;
    }
    if (i < 3 * 192 * 96) {
        int l = i / (192 * 96), r = i % (192 * 96);
        int n = r / 192, k = r % 192;
        const float* Wn = (l == 0) ? Wn1 : (l == 1) ? Wn2 : Wn3;
        const float* Ws = (l == 0) ? Ws1 : (l == 1) ? Ws2 : Ws3;
        float v = (k < 96) ? Wn[k * 96 + n] : Ws[(k - 96) * 96 + n];
        WbT[i] = f2b(v);
    }
}

// ---------- fused layer: 16 threads/node (4-way edge split, shfl combine) + MFMA ----------
// hin: [N][RPAD] bf16 padded rows. 16 nodes/block, 256 threads (4 waves):
//   nl = t>>4 (node 0..15), h = (t>>2)&3 (edge quarter, stride 4), q = t&3 (16B chunk).
// Gather: 4 edges per iteration -> 12 dwordx4 in flight (typical quarter = one iter).
// Quarters combine via shfl_xor(4/8) in-wave. One barrier before MFMA.
// out_bf16==0 (layer 3): pooling fused — per-block LDS f32 accum, then atomics.
__global__ __launch_bounds__(256, 4) void k_layer(
    const unsigned short* __restrict__ hin,
    const unsigned short* __restrict__ csr_g,
    const int* __restrict__ ndesc,
    const unsigned short* __restrict__ WbT,  // [96][192] bf16 (n-major)
    const float* __restrict__ bias,
    unsigned short* __restrict__ hout, int relu, int out_bf16,
    const int* __restrict__ batch, float* __restrict__ pools) {
    __shared__ unsigned short A[LBK * LSTRIDE];  // 6.4 KB
    __shared__ float pl[2 * F];                  // layer-3 pooling accum
    int t = threadIdx.x;
    int row0 = blockIdx.x * LBK;
    int nl = t >> 4;
    int h = (t >> 2) & 3;
    int q = t & 3;
    int node = row0 + nl;                 // always < N_NODES (50000 = 3125*16)
    int deg = ndesc[node];
    if (deg > DMAX) deg = DMAX;
    size_t ebase = (size_t)node << 6;

    if (!out_bf16 && t < 2 * F) pl[t] = 0.f;

    // --- self row -> LDS (h==0 lanes cover all 192B) ---
    if (h == 0) {
        const uint4* sp = (const uint4*)(hin + (size_t)node * RPAD + (q << 3));
        uint4 s0 = sp[0], s1 = sp[4], s2 = sp[8];
        *(uint4*)&A[nl * LSTRIDE + 96 + 0 * 32 + q * 8] = s0;
        *(uint4*)&A[nl * LSTRIDE + 96 + 1 * 32 + q * 8] = s1;
        *(uint4*)&A[nl * LSTRIDE + 96 + 2 * 32 + q * 8] = s2;
    }

    // --- gather: quarter h handles edges e ≡ h (mod 4); 4 edges/iter = 12 loads in flight ---
    float ac[24];
#pragma unroll
    for (int k = 0; k < 24; k++) ac[k] = 0.f;
    {
        int e = h;
        for (; e + 12 < deg; e += 16) {
            int s0 = csr_g[ebase + e];
            int s1 = csr_g[ebase + e + 4];
            int s2 = csr_g[ebase + e + 8];
            int s3 = csr_g[ebase + e + 12];
            const uint4* p0 = (const uint4*)(hin + ((size_t)s0 << 7) + (q << 3));
            const uint4* p1 = (const uint4*)(hin + ((size_t)s1 << 7) + (q << 3));
            const uint4* p2 = (const uint4*)(hin + ((size_t)s2 << 7) + (q << 3));
            const uint4* p3 = (const uint4*)(hin + ((size_t)s3 << 7) + (q << 3));
            uint4 a0 = p0[0], a1 = p0[4], a2 = p0[8];
            uint4 b0 = p1[0], b1 = p1[4], b2 = p1[8];
            uint4 c0 = p2[0], c1 = p2[4], c2 = p2[8];
            uint4 d0 = p3[0], d1 = p3[4], d2 = p3[8];
            addu4(ac + 0, a0); addu4(ac + 8, a1); addu4(ac + 16, a2);
            addu4(ac + 0, b0); addu4(ac + 8, b1); addu4(ac + 16, b2);
            addu4(ac + 0, c0); addu4(ac + 8, c1); addu4(ac + 16, c2);
            addu4(ac + 0, d0); addu4(ac + 8, d1); addu4(ac + 16, d2);
        }
        for (; e < deg; e += 4) {
            int s0 = csr_g[ebase + e];
            const uint4* p0 = (const uint4*)(hin + ((size_t)s0 << 7) + (q << 3));
            uint4 a0 = p0[0], a1 = p0[4], a2 = p0[8];
            addu4(ac + 0, a0); addu4(ac + 8, a1); addu4(ac + 16, a2);
        }
    }

    // --- combine quarters in-wave: lane bits [3:2] = h ---
#pragma unroll
    for (int k = 0; k < 24; k++) {
        ac[k] += __shfl_xor(ac[k], 4, 64);
        ac[k] += __shfl_xor(ac[k], 8, 64);
    }

    // --- pack aggregated features to LDS (h==0 lanes) ---
    if (h == 0) {
#pragma unroll
        for (int j = 0; j < 3; j++) {
            uint4 pk;
            pk.x = ((unsigned int)f2b(ac[j * 8 + 1]) << 16) | f2b(ac[j * 8 + 0]);
            pk.y = ((unsigned int)f2b(ac[j * 8 + 3]) << 16) | f2b(ac[j * 8 + 2]);
            pk.z = ((unsigned int)f2b(ac[j * 8 + 5]) << 16) | f2b(ac[j * 8 + 4]);
            pk.w = ((unsigned int)f2b(ac[j * 8 + 7]) << 16) | f2b(ac[j * 8 + 6]);
            *(uint4*)&A[nl * LSTRIDE + j * 32 + q * 8] = pk;
        }
    }
    __syncthreads();

    // --- MFMA: wave w computes nt in {w, w+4} (waves 0,1: 2 tiles; 2,3: 1) ---
    int wave = t >> 6;
    int lane = t & 63;
    int m = lane & 15;
    int ko = (lane >> 4) * 8;
    f32x4 acc[2];
    acc[0] = (f32x4){0.f, 0.f, 0.f, 0.f};
    acc[1] = (f32x4){0.f, 0.f, 0.f, 0.f};
    int ntc = (wave < 2) ? 2 : 1;
#pragma unroll
    for (int j = 0; j < 3; j++) {
        bf16x8 a0 = *(bf16x8*)&A[m * LSTRIDE + j * 32 + ko];
        bf16x8 a1 = *(bf16x8*)&A[m * LSTRIDE + 96 + j * 32 + ko];
        for (int ii = 0; ii < ntc; ii++) {
            int nt = wave + ii * 4;
            bf16x8 b0 = *(const bf16x8*)(WbT + (size_t)(nt * 16 + m) * 192 + j * 32 + ko);
            acc[ii] = __builtin_amdgcn_mfma_f32_16x16x32_bf16(a0, b0, acc[ii], 0, 0, 0);
            bf16x8 b1 = *(const bf16x8*)(WbT + (size_t)(nt * 16 + m) * 192 + 96 + j * 32 + ko);
            acc[ii] = __builtin_amdgcn_mfma_f32_16x16x32_bf16(a1, b1, acc[ii], 0, 0, 0);
        }
    }

    if (out_bf16) {
        for (int ii = 0; ii < ntc; ii++) {
            int col = (wave + ii * 4) * 16 + m;
            float bv = bias[col];
#pragma unroll
            for (int r = 0; r < 4; r++) {
                int rl = ((lane >> 4) << 2) + r;
                int onode = row0 + rl;
                float v = acc[ii][r] + bv;
                if (relu) v = fmaxf(v, 0.f);
                hout[(size_t)onode * RPAD + col] = f2b(v);
            }
        }
    } else {
        // layer 3: fused mean-pool accumulation (block spans <=2 graphs normally)
        int gA = batch[row0];
        for (int ii = 0; ii < ntc; ii++) {
            int col = (wave + ii * 4) * 16 + m;
            float bv = bias[col];
            float s0 = 0.f, s1 = 0.f;
#pragma unroll
            for (int r = 0; r < 4; r++) {
                int rl = ((lane >> 4) << 2) + r;
                int onode = row0 + rl;
                float v = acc[ii][r] + bv;
                int slot = batch[onode] - gA;
                if (slot == 0) s0 += v;
                else if (slot == 1) s1 += v;
                else atomicAdd(&pools[(size_t)(gA + slot) * F + col], v);  // freak case
            }
            if (s0 != 0.f) atomicAdd(&pl[col], s0);
            if (s1 != 0.f) atomicAdd(&pl[F + col], s1);
        }
        __syncthreads();
        if (t < 2 * F) {
            int gl = t / F;
            float v = pl[t];
            if (v != 0.f && gA + gl < NG)
                atomicAdd(&pools[(size_t)(gA + gl) * F + (t % F)], v);
        }
    }
}

// ---------- head: divide pooled sums by counts, apply classifier ----------
__global__ __launch_bounds__(128) void k_head(const float* __restrict__ pools,
                                              const int* __restrict__ batch,
                                              const float* __restrict__ Wl,
                                              const float* __restrict__ bl,
                                              float* __restrict__ out) {
    __shared__ float pool[F];
    __shared__ int bounds[2];
    int g = blockIdx.x;
    int t = threadIdx.x;
    if (t < 2) {
        int target = g + t;
        int lo = 0, hi = N_NODES;
        while (lo < hi) {
            int mid = (lo + hi) >> 1;
            if (batch[mid] < target) lo = mid + 1; else hi = mid;
        }
        bounds[t] = lo;
    }
    __syncthreads();
    float inv = 1.f / fmaxf((float)(bounds[1] - bounds[0]), 1.f);
    if (t < F) pool[t] = pools[(size_t)g * F + t] * inv;
    __syncthreads();
    if (t < NC) {
        float s = bl[t];
#pragma unroll 8
        for (int k = 0; k < F; k++) s += pool[k] * Wl[k * NC + t];
        out[g * NC + t] = s;
    }
}

extern "C" void kernel_launch(void* const* d_in, const int* in_sizes, int n_in,
                              void* d_out, int out_size, void* d_ws, size_t ws_size,
                              hipStream_t stream) {
    const float* x   = (const float*)d_in[0];
    const int* ei    = (const int*)d_in[1];
    const int* batch = (const int*)d_in[3];
    const float* Wn1 = (const float*)d_in[4];
    const float* Ws1 = (const float*)d_in[5];
    const float* b1  = (const float*)d_in[6];
    const float* Wn2 = (const float*)d_in[7];
    const float* Ws2 = (const float*)d_in[8];
    const float* b2  = (const float*)d_in[9];
    const float* Wn3 = (const float*)d_in[10];
    const float* Ws3 = (const float*)d_in[11];
    const float* b3  = (const float*)d_in[12];
    const float* Wl  = (const float*)d_in[13];
    const float* bl  = (const float*)d_in[14];
    float* out = (float*)d_out;

    char* w = (char*)d_ws;
    unsigned short* xb_t  = (unsigned short*)w; w += (size_t)N_NODES * RPAD * 2;
    unsigned short* h1_t  = (unsigned short*)w; w += (size_t)N_NODES * RPAD * 2;
    unsigned short* h2_t  = (unsigned short*)w; w += (size_t)N_NODES * RPAD * 2;
    unsigned short* WbT   = (unsigned short*)w; w += (size_t)3 * 192 * 96 * 2;
    w = (char*)(((size_t)w + 255) & ~(size_t)255);
    unsigned short* csr_g = (unsigned short*)w; w += (size_t)N_NODES * DMAX * 2;
    int* ndesc           = (int*)w;             w += (size_t)N_NODES * 4;
    float* pools         = (float*)w;           w += (size_t)NG * F * 4;  // adjacent to ndesc: one memset

    hipMemsetAsync(ndesc, 0, (size_t)N_NODES * 4 + (size_t)NG * F * 4, stream);
    k_prepfill<<<(N_NODES * 24 + 255) / 256, 256, 0, stream>>>(
        x, ei, Wn1, Ws1, Wn2, Ws2, Wn3, Ws3, xb_t, WbT, ndesc, csr_g);

    k_layer<<<NLB, 256, 0, stream>>>(xb_t, csr_g, ndesc, WbT,                b1, h1_t, 1, 1, batch, pools);
    k_layer<<<NLB, 256, 0, stream>>>(h1_t, csr_g, ndesc, WbT + 192 * 96,     b2, h2_t, 1, 1, batch, pools);
    k_layer<<<NLB, 256, 0, stream>>>(h2_t, csr_g, ndesc, WbT + 2 * 192 * 96, b3, h2_t, 0, 0, batch, pools);

    k_head<<<NG, 128, 0, stream>>>(pools, batch, Wl, bl, out);
}